// Round 7
// baseline (2519.478 us; speedup 1.0000x reference)
//
#include <hip/hip_runtime.h>
#include <cstdint>

#define BB 256
#define TT 4096
#define FDIM 16
#define HH 128
#define CH 32           // timesteps per chunk
#define NCH (TT / CH)   // 128 chunks
#define NPROD 5         // producer waves 0-4; waves 5,6,7 = scan1,scan2,scan3
#define NTHR 512

typedef unsigned long long u64;
typedef float f32x2 __attribute__((ext_vector_type(2)));
typedef uint32_t u32x4 __attribute__((ext_vector_type(4)));

// ---------------------------------------------------------------------------
// asm helpers. All ledgered memory ops are asm volatile => issue order ==
// program order; counted s_waitcnt ledgers are exact. After every wait:
// sched_barrier(0) (skill rule #18).
// ---------------------------------------------------------------------------
__device__ __forceinline__ uint32_t lds_addr32(const void* p) {
  return (uint32_t)(uintptr_t)p;
}
__device__ __forceinline__ f32x2 glb_load_b64(uint32_t voff, const void* base) {
  f32x2 d;
  asm volatile("global_load_dwordx2 %0, %1, %2" : "=v"(d) : "v"(voff), "s"(base));
  return d;
}
__device__ __forceinline__ void ds_write_b128_at(uint32_t addr, u32x4 v) {
  asm volatile("ds_write_b128 %0, %1" ::"v"(addr), "v"(v));
}
#define WAIT_VM(N)                                          \
  {                                                         \
    asm volatile("s_waitcnt vmcnt(" #N ")" ::: "memory");   \
    __builtin_amdgcn_sched_barrier(0);                      \
  }
#define WAIT_LGKM(N)                                        \
  {                                                         \
    asm volatile("s_waitcnt lgkmcnt(" #N ")" ::: "memory"); \
    __builtin_amdgcn_sched_barrier(0);                      \
  }
#define DSR64(D, A, OFF) \
  asm volatile("ds_read_b64 %0, %1 offset:" #OFF : "=v"(D) : "v"(A));
#define DS_READ_OFF(D, A, OFF) \
  asm volatile("ds_read_b32 %0, %1 offset:" #OFF : "=v"(D) : "v"(A));

// Packed fp32 add (two independent IEEE-rn adds; dataflow pins association).
__device__ __forceinline__ f32x2 pk_add(f32x2 a, f32x2 b) {
  f32x2 d;
  asm("v_pk_add_f32 %0, %1, %2" : "=v"(d) : "v"(a), "v"(b));
  return d;
}
__device__ __forceinline__ u64 rfl64(u64 x) {
  uint32_t lo = (uint32_t)__builtin_amdgcn_readfirstlane((int)(uint32_t)x);
  uint32_t hi = (uint32_t)__builtin_amdgcn_readfirstlane((int)(uint32_t)(x >> 32));
  return ((u64)hi << 32) | lo;
}
// 64-lane DPP sum; result valid in lane 63 (same op sequence as rounds 1-6).
__device__ __forceinline__ float wave_red_add63(float v) {
#define DPP_ADD(c)                                                             \
  v += __int_as_float(                                                         \
      __builtin_amdgcn_update_dpp(0, __float_as_int(v), c, 0xF, 0xF, true))
  DPP_ADD(0x111);
  DPP_ADD(0x112);
  DPP_ADD(0x114);
  DPP_ADD(0x118);
  DPP_ADD(0x142);
  DPP_ADD(0x143);
#undef DPP_ADD
  return v;
}

// ---------------------------------------------------------------------------
// Kernel 0: transposed weights in workspace.
// w1t: 64 rows of 512B; rows 0..31 = (W1[l][j], W1[64+l][j]); 32..63 zero
//      (guard-bit sentinels for branchless 16-slot extraction).
// w2t: 129 rows; rows 0..127 real, row 128 zero (sentinel).
// ---------------------------------------------------------------------------
__global__ __launch_bounds__(64) void snn_prep(const float* __restrict__ W1,
                                               const float* __restrict__ W2,
                                               f32x2* __restrict__ w1t,
                                               f32x2* __restrict__ w2t) {
  const int l = threadIdx.x;
  for (int j = 0; j < 64; ++j)
    w1t[j * 64 + l] = (j < 32) ? f32x2{W1[l * 32 + j], W1[(64 + l) * 32 + j]}
                               : f32x2{0.f, 0.f};
  for (int j = 0; j < 129; ++j)
    w2t[j * 64 + l] = (j < 128) ? f32x2{W2[l * 128 + j], W2[(64 + l) * 128 + j]}
                                : f32x2{0.f, 0.f};
}

// ---------------------------------------------------------------------------
// Kernel 1: delta encode -> 32-bit masks (verbatim from passing rounds 4-6).
// ---------------------------------------------------------------------------
__global__ __launch_bounds__(64) void snn_encode(const float* __restrict__ x,
                                                 uint32_t* __restrict__ masks) {
  __shared__ float tile[2][4][64][16];  // 32 KiB
  const int lane = threadIdx.x;
  const int sub = lane >> 4;
  const int f = lane & 15;
  const int b0 = blockIdx.x * 4;
  float ref = x[(size_t)(b0 + sub) * (TT * FDIM) + f];

  const float4* xv = (const float4*)x;
  float4 ld[16];
#define K1_ISSUE(G)                                                           \
  _Pragma("unroll") for (int k = 0; k < 16; ++k) {                            \
    int idx4 = k * 64 + lane;                                                 \
    int bl = idx4 >> 8;                                                       \
    int r = idx4 & 255;                                                       \
    ld[k] = xv[(size_t)(b0 + bl) * (TT * 4) + (size_t)(G) * 256 + r];         \
  }
#define K1_WRITE(BUF)                                                         \
  _Pragma("unroll") for (int k = 0; k < 16; ++k) {                            \
    int idx4 = k * 64 + lane;                                                 \
    int bl = idx4 >> 8;                                                       \
    int r = idx4 & 255;                                                       \
    ((float4*)&tile[BUF][bl][0][0])[r] = ld[k];                               \
  }
#define CHUNK_ISSUE(ARR, A)                                                   \
  {                                                                           \
    DS_READ_OFF(ARR[0], A, 0);                                                \
    DS_READ_OFF(ARR[1], A, 64);                                               \
    DS_READ_OFF(ARR[2], A, 128);                                              \
    DS_READ_OFF(ARR[3], A, 192);                                              \
    DS_READ_OFF(ARR[4], A, 256);                                              \
    DS_READ_OFF(ARR[5], A, 320);                                              \
    DS_READ_OFF(ARR[6], A, 384);                                              \
    DS_READ_OFF(ARR[7], A, 448);                                              \
  }
#define PROC8(ARR, TBASE)                                                     \
  _Pragma("unroll") for (int i = 0; i < 8; ++i) {                             \
    float cur = ARR[i];                                                       \
    float diff = cur - ref;                                                   \
    bool onb = diff >= 0.5f;                                                  \
    bool offb = diff <= -0.5f;                                                \
    u64 bon = __ballot(onb);                                                  \
    u64 boff = __ballot(offb);                                                \
    ref = (onb || offb) ? cur : ref;                                          \
    if (f == 0) {                                                             \
      uint32_t mk = (uint32_t)((bon >> (sub * 16)) & 0xFFFFull) |             \
                    ((uint32_t)((boff >> (sub * 16)) & 0xFFFFull) << 16);     \
      masks[(size_t)(b0 + sub) * TT + ((TBASE) + i)] = mk;                    \
    }                                                                         \
  }

  const uint32_t tbase =
      lds_addr32(&tile[0][0][0][0]) + (uint32_t)sub * 4096u + (uint32_t)f * 4u;

  K1_ISSUE(0);
  K1_WRITE(0);
  WAIT_LGKM(0);
  for (int g = 0; g < TT / 64; ++g) {
    if (g + 1 < TT / 64) K1_ISSUE(g + 1);
    const int buf = g & 1;
    const uint32_t caddr = tbase + (uint32_t)buf * 16384u;
    float va[8], vb[8];
    CHUNK_ISSUE(va, caddr);
#pragma unroll
    for (int c = 0; c < 8; ++c) {
      if (c < 7) {
        uint32_t an = caddr + (uint32_t)(c + 1) * 512u;
        if (c & 1) {
          CHUNK_ISSUE(va, an);
        } else {
          CHUNK_ISSUE(vb, an);
        }
        WAIT_LGKM(8);
      } else {
        WAIT_LGKM(0);
      }
      if (c & 1) {
        PROC8(vb, g * 64 + c * 8);
      } else {
        PROC8(va, g * 64 + c * 8);
      }
    }
    if (g + 1 < TT / 64) {
      K1_WRITE((g + 1) & 1);
      WAIT_LGKM(0);
    }
  }
#undef PROC8
#undef CHUNK_ISSUE
#undef K1_WRITE
#undef K1_ISSUE
}

// ---------------------------------------------------------------------------
// Kernel 2: specialized-wave SNN core. One block (8 waves) per batch.
// iter k (one __syncthreads at top, chunk-parity double buffers):
//   waves 0-4: C1(k) [16-slot], C2(k-2) [24-slot], C3(k-4) DPP tasks
//   wave 5:    scan1(k-1): C1 -> LIF1 -> S1 ballots
//   wave 6:    scan2(k-3): C2 -> LIF2 -> S2 ballots
//   wave 7:    scan3(k-5): C3 -> LIF3 -> out
// Dependency check (all reads >=1 barrier behind writes, parities disjoint):
//   C2(k-2) reads S1(k-2) written by scan1 at iter k-1; scan1(k-1) reads
//   C1(k-1) written at iter k-1; C3(k-4) reads S2(k-4) written at iter k-1;
//   scan3(k-5) reads C3(k-5) written at iter k-1.
// ---------------------------------------------------------------------------
__global__ __launch_bounds__(NTHR, 1) void snn_core7(
    const uint32_t* __restrict__ masks, const f32x2* __restrict__ w1t,
    const f32x2* __restrict__ w2t, const float* __restrict__ b1,
    const float* __restrict__ b2, const float* __restrict__ W3,
    const float* __restrict__ b3, float* __restrict__ out) {
  __shared__ __align__(16) uint32_t mks[TT];   // 16 KB input masks
  __shared__ f32x2 C1b[2][CH][64];             // 32 KB
  __shared__ f32x2 C2b[2][CH][64];             // 32 KB
  __shared__ f32x2 C3b[2][CH];                 // 512 B
  __shared__ __align__(16) u64 S1[2][CH][2];   // 1 KB spk1 ballots
  __shared__ __align__(16) u64 S2[2][CH][2];   // 1 KB spk2 ballots

  const int tid = threadIdx.x;
  const int lane = tid & 63;
  const int wv = tid >> 6;
  const int b = blockIdx.x;
  const uint32_t lane8 = (uint32_t)lane * 8u;

  {  // stage this batch's masks into LDS (coalesced)
    const u32x4* src = (const u32x4*)(masks + (size_t)b * TT);
    u32x4* dst = (u32x4*)mks;
    for (int i = tid; i < TT / 4; i += NTHR) dst[i] = src[i];
  }
  const f32x2 bias1 = {b1[lane], b1[64 + lane]};
  const f32x2 bias2 = {b2[lane], b2[64 + lane]};
  const float w30a = W3[lane], w30b = W3[64 + lane];
  const float w31a = W3[128 + lane], w31b = W3[192 + lane];
  const float b30 = b3[0], b31 = b3[1];
  float m1a = 0.f, m1b = 0.f, m2a = 0.f, m2b = 0.f, m3x = 0.f, m3y = 0.f;
  float2* outv = (float2*)out;
  __syncthreads();

// ---- producer task helpers (vm ledger: 16 loads for C1, 24 for C2) ----
#define EXTRACT(J)                                                            \
  {                                                                           \
    bool av_ = (a_ != 0);                                                     \
    bool bv_ = (b_ != 0);                                                     \
    uint32_t ja_ = av_ ? (uint32_t)__builtin_ctzll(a_) : 0u;                  \
    uint32_t jb_ = bv_ ? 64u + (uint32_t)__builtin_ctzll(b_) : 128u;          \
    J = av_ ? ja_ : jb_;                                                      \
    u64 an_ = a_ & (a_ - 1);                                                  \
    u64 bn_ = b_ & (b_ - 1);                                                  \
    b_ = (!av_ && bv_) ? bn_ : b_;                                            \
    a_ = av_ ? an_ : a_;                                                      \
  }
#define P_ISSUE(TASK, BUF, RA, RB)                                            \
  {                                                                           \
    if ((TASK) < CH) { /* C1 task, chunk k: <=16 set bits guaranteed */       \
      uint32_t mk_ = (k < NCH) ? mks[k * CH + (TASK)] : 0u;                   \
      mk_ = (uint32_t)__builtin_amdgcn_readfirstlane((int)mk_);               \
      u64 mm_ = (u64)mk_ | 0x0000FFFF00000000ull; /* guard bits 32..47 */     \
      _Pragma("unroll") for (int s = 0; s < 16; ++s) {                        \
        uint32_t j_ = (uint32_t)__builtin_ctzll(mm_);                         \
        mm_ &= mm_ - 1;                                                       \
        BUF[s] = glb_load_b64((j_ << 9) + lane8, w1t);                        \
      }                                                                       \
      RA = 0;                                                                 \
      RB = 0;                                                                 \
    } else { /* C2 task, chunk k-2 */                                         \
      int c2_ = k - 2;                                                        \
      bool ok_ = (c2_ >= 0) && (c2_ < NCH);                                   \
      u64 a_ = ok_ ? S1[c2_ & 1][(TASK) - CH][0] : 0ull;                      \
      u64 b_ = ok_ ? S1[c2_ & 1][(TASK) - CH][1] : 0ull;                      \
      a_ = rfl64(a_);                                                         \
      b_ = rfl64(b_);                                                         \
      _Pragma("unroll") for (int s = 0; s < 24; ++s) {                        \
        uint32_t j_;                                                          \
        EXTRACT(j_);                                                          \
        BUF[s] = glb_load_b64((j_ << 9) + lane8, w2t);                        \
      }                                                                       \
      RA = a_;                                                                \
      RB = b_;                                                                \
    }                                                                         \
  }
#define P_CONSUME(TASK, BUF, RA, RB)                                          \
  {                                                                           \
    if ((TASK) < CH) {                                                        \
      if (k < NCH) {                                                          \
        f32x2 c_ = {0.f, 0.f};                                                \
        _Pragma("unroll") for (int s = 0; s < 16; ++s) c_ = pk_add(c_, BUF[s]); \
        c_ = pk_add(c_, bias1);                                               \
        C1b[k & 1][(TASK)][lane] = c_;                                        \
      }                                                                       \
    } else {                                                                  \
      int c2_ = k - 2;                                                        \
      if (c2_ >= 0 && c2_ < NCH) {                                            \
        f32x2 c_ = {0.f, 0.f};                                                \
        _Pragma("unroll") for (int s = 0; s < 24; ++s) c_ = pk_add(c_, BUF[s]); \
        u64 ta_ = RA; /* rare >24-spike tails: exact A-then-B order */        \
        while (ta_) {                                                         \
          uint32_t j_ = (uint32_t)__builtin_ctzll(ta_);                       \
          ta_ &= ta_ - 1;                                                     \
          f32x2 tw_ = glb_load_b64((j_ << 9) + lane8, w2t);                   \
          WAIT_VM(0);                                                         \
          c_ = pk_add(c_, tw_);                                               \
        }                                                                     \
        u64 tb_ = RB;                                                         \
        while (tb_) {                                                         \
          uint32_t j_ = 64u + (uint32_t)__builtin_ctzll(tb_);                 \
          tb_ &= tb_ - 1;                                                     \
          f32x2 tw_ = glb_load_b64((j_ << 9) + lane8, w2t);                   \
          WAIT_VM(0);                                                         \
          c_ = pk_add(c_, tw_);                                               \
        }                                                                     \
        c_ = pk_add(c_, bias2);                                               \
        C2b[c2_ & 1][(TASK) - CH][lane] = c_;                                 \
      }                                                                       \
    }                                                                         \
  }
#define C3_TASK(T3)                                                           \
  {                                                                           \
    int c3_ = k - 4;                                                          \
    if (c3_ >= 0 && c3_ < NCH) {                                              \
      u64 a_ = rfl64(S2[c3_ & 1][(T3)][0]);                                   \
      u64 b_ = rfl64(S2[c3_ & 1][(T3)][1]);                                   \
      float v0 = (((a_ >> lane) & 1) ? w30a : 0.f) +                          \
                 (((b_ >> lane) & 1) ? w30b : 0.f);                           \
      float v1 = (((a_ >> lane) & 1) ? w31a : 0.f) +                          \
                 (((b_ >> lane) & 1) ? w31b : 0.f);                           \
      float r0 = wave_red_add63(v0);                                          \
      float r1 = wave_red_add63(v1);                                          \
      if (lane == 63) C3b[c3_ & 1][(T3)] = f32x2{r0 + b30, r1 + b31};         \
    }                                                                         \
  }

// ---- scan helpers: batch the whole chunk into registers, one wait, then
// 32 pure-register LIF steps (ballot + lane-0 pack write off the chain) ----
#define ISSUE32_512(ARR, A)                                                   \
  {                                                                           \
    DSR64(ARR[0], A, 0);     DSR64(ARR[1], A, 512);                           \
    DSR64(ARR[2], A, 1024);  DSR64(ARR[3], A, 1536);                          \
    DSR64(ARR[4], A, 2048);  DSR64(ARR[5], A, 2560);                          \
    DSR64(ARR[6], A, 3072);  DSR64(ARR[7], A, 3584);                          \
    DSR64(ARR[8], A, 4096);  DSR64(ARR[9], A, 4608);                          \
    DSR64(ARR[10], A, 5120); DSR64(ARR[11], A, 5632);                         \
    DSR64(ARR[12], A, 6144); DSR64(ARR[13], A, 6656);                         \
    DSR64(ARR[14], A, 7168); DSR64(ARR[15], A, 7680);                         \
    DSR64(ARR[16], A, 8192); DSR64(ARR[17], A, 8704);                         \
    DSR64(ARR[18], A, 9216); DSR64(ARR[19], A, 9728);                         \
    DSR64(ARR[20], A, 10240); DSR64(ARR[21], A, 10752);                       \
    DSR64(ARR[22], A, 11264); DSR64(ARR[23], A, 11776);                       \
    DSR64(ARR[24], A, 12288); DSR64(ARR[25], A, 12800);                       \
    DSR64(ARR[26], A, 13312); DSR64(ARR[27], A, 13824);                       \
    DSR64(ARR[28], A, 14336); DSR64(ARR[29], A, 14848);                       \
    DSR64(ARR[30], A, 15360); DSR64(ARR[31], A, 15872);                       \
  }
#define ISSUE32_8(ARR, A)                                                     \
  {                                                                           \
    DSR64(ARR[0], A, 0);   DSR64(ARR[1], A, 8);                               \
    DSR64(ARR[2], A, 16);  DSR64(ARR[3], A, 24);                              \
    DSR64(ARR[4], A, 32);  DSR64(ARR[5], A, 40);                              \
    DSR64(ARR[6], A, 48);  DSR64(ARR[7], A, 56);                              \
    DSR64(ARR[8], A, 64);  DSR64(ARR[9], A, 72);                              \
    DSR64(ARR[10], A, 80); DSR64(ARR[11], A, 88);                             \
    DSR64(ARR[12], A, 96); DSR64(ARR[13], A, 104);                            \
    DSR64(ARR[14], A, 112); DSR64(ARR[15], A, 120);                           \
    DSR64(ARR[16], A, 128); DSR64(ARR[17], A, 136);                           \
    DSR64(ARR[18], A, 144); DSR64(ARR[19], A, 152);                           \
    DSR64(ARR[20], A, 160); DSR64(ARR[21], A, 168);                           \
    DSR64(ARR[22], A, 176); DSR64(ARR[23], A, 184);                           \
    DSR64(ARR[24], A, 192); DSR64(ARR[25], A, 200);                           \
    DSR64(ARR[26], A, 208); DSR64(ARR[27], A, 216);                           \
    DSR64(ARR[28], A, 224); DSR64(ARR[29], A, 232);                           \
    DSR64(ARR[30], A, 240); DSR64(ARR[31], A, 248);                           \
  }
#define SCAN_L(CHK, CBUF, SBUF, MA, MB)                                       \
  {                                                                           \
    const int par_ = (CHK) & 1;                                               \
    const uint32_t rb_ = lds_addr32(&CBUF[par_][0][0]) + lane8;               \
    const uint32_t sb_ = lds_addr32(&SBUF[par_][0][0]);                       \
    f32x2 arr_[32];                                                           \
    ISSUE32_512(arr_, rb_);                                                   \
    WAIT_LGKM(0);                                                             \
    _Pragma("unroll") for (int i = 0; i < 32; ++i) {                          \
      f32x2 cv_ = arr_[i];                                                    \
      float n0_ = __fadd_rn(__fmul_rn(0.9f, MA), cv_.x);                      \
      float n1_ = __fadd_rn(__fmul_rn(0.9f, MB), cv_.y);                      \
      MA = (MA > 1.f) ? (n0_ - 1.f) : n0_;                                    \
      MB = (MB > 1.f) ? (n1_ - 1.f) : n1_;                                    \
      u64 s0_ = __ballot(MA > 1.f);                                           \
      u64 s1_ = __ballot(MB > 1.f);                                           \
      if (lane == 0)                                                          \
        ds_write_b128_at(sb_ + (uint32_t)(i * 16),                            \
                         u32x4{(uint32_t)s0_, (uint32_t)(s0_ >> 32),          \
                               (uint32_t)s1_, (uint32_t)(s1_ >> 32)});        \
    }                                                                         \
    WAIT_LGKM(0); /* drain asm writes before barrier */                       \
  }
#define SCAN3(CHK)                                                            \
  {                                                                           \
    const int par_ = (CHK) & 1;                                               \
    const uint32_t cb_ = lds_addr32(&C3b[par_][0]);                           \
    f32x2 arr_[32];                                                           \
    ISSUE32_8(arr_, cb_);                                                     \
    WAIT_LGKM(0);                                                             \
    _Pragma("unroll") for (int i = 0; i < 32; ++i) {                          \
      f32x2 c3_ = arr_[i];                                                    \
      float e0_ = __fadd_rn(__fmul_rn(0.9f, m3x), c3_.x);                     \
      float e1_ = __fadd_rn(__fmul_rn(0.9f, m3y), c3_.y);                     \
      m3x = (m3x > 1.f) ? (e0_ - 1.f) : e0_;                                  \
      m3y = (m3y > 1.f) ? (e1_ - 1.f) : e1_;                                  \
      if (lane == 0)                                                          \
        outv[(size_t)((CHK)*CH + i) * BB + b] = make_float2(m3x, m3y);        \
    }                                                                         \
  }

  // ================= chunk-synchronous main pipeline =================
  for (int k = 0; k < NCH + 5; ++k) {
    __syncthreads();
    if (wv < NPROD) {
      // tasks 0..31 = C1(chunk k) [16 loads], 32..63 = C2(chunk k-2) [24].
      // 2-deep ping-pong; wait count = loads of the just-issued task.
      f32x2 P[24], Q[24];
      u64 raP = 0, rbP = 0, raQ = 0, rbQ = 0;
      int ti = wv;
      P_ISSUE(ti, P, raP, rbP);
      for (;;) {
        int tn = ti + NPROD;
        if (tn < 2 * CH) {
          P_ISSUE(tn, Q, raQ, rbQ);
          if (tn < CH) {
            WAIT_VM(16);
          } else {
            WAIT_VM(24);
          }
        } else {
          WAIT_VM(0);
        }
        P_CONSUME(ti, P, raP, rbP);
        if (tn >= 2 * CH) break;
        ti = tn + NPROD;
        if (ti < 2 * CH) {
          P_ISSUE(ti, P, raP, rbP);
          if (ti < CH) {
            WAIT_VM(16);
          } else {
            WAIT_VM(24);
          }
        } else {
          WAIT_VM(0);
        }
        P_CONSUME(tn, Q, raQ, rbQ);
        if (ti >= 2 * CH) break;
      }
      for (int t3 = wv; t3 < CH; t3 += NPROD) {
        C3_TASK(t3);
      }
    } else if (wv == 5) {
      if (k >= 1 && k - 1 < NCH) SCAN_L(k - 1, C1b, S1, m1a, m1b);
    } else if (wv == 6) {
      if (k >= 3 && k - 3 < NCH) SCAN_L(k - 3, C2b, S2, m2a, m2b);
    } else {
      if (k >= 5 && k - 5 < NCH) SCAN3(k - 5);
    }
  }
#undef SCAN3
#undef SCAN_L
#undef ISSUE32_8
#undef ISSUE32_512
#undef C3_TASK
#undef P_CONSUME
#undef P_ISSUE
#undef EXTRACT
}

extern "C" void kernel_launch(void* const* d_in, const int* in_sizes, int n_in,
                              void* d_out, int out_size, void* d_ws,
                              size_t ws_size, hipStream_t stream) {
  const float* x = (const float*)d_in[0];
  const float* W1 = (const float*)d_in[1];
  const float* b1 = (const float*)d_in[2];
  const float* W2 = (const float*)d_in[3];
  const float* b2 = (const float*)d_in[4];
  const float* W3 = (const float*)d_in[5];
  const float* b3 = (const float*)d_in[6];
  float* out = (float*)d_out;

  uint32_t* masks = (uint32_t*)d_ws;                         // 4 MiB
  char* wbase = (char*)d_ws + (size_t)BB * TT * 4;
  f32x2* w1t = (f32x2*)wbase;                                // 32768 B
  f32x2* w2t = (f32x2*)(wbase + 32768);                      // 66048 B

  snn_prep<<<1, 64, 0, stream>>>(W1, W2, w1t, w2t);
  snn_encode<<<BB / 4, 64, 0, stream>>>(x, masks);
  snn_core7<<<BB, NTHR, 0, stream>>>(masks, w1t, w2t, b1, b2, W3, b3, out);
}

// Round 8
// 1650.265 us; speedup vs baseline: 1.5267x; 1.5267x over previous
//
#include <hip/hip_runtime.h>
#include <cstdint>

#define BB 256
#define TT 4096
#define FDIM 16
#define HH 128
#define CH 32           // timesteps per chunk
#define NCH (TT / CH)   // 128 chunks
#define NPROD 10        // producer waves 0-9; wave 10 = scan1, wave 11 = aux
#define NTHR 768

typedef unsigned long long u64;
typedef float f32x2 __attribute__((ext_vector_type(2)));
typedef uint32_t u32x4 __attribute__((ext_vector_type(4)));

// ---------------------------------------------------------------------------
// asm helpers. All ledgered memory ops are asm volatile => issue order ==
// program order; counted s_waitcnt ledgers are exact. After every wait:
// sched_barrier(0) (skill rule #18).
// ---------------------------------------------------------------------------
__device__ __forceinline__ uint32_t lds_addr32(const void* p) {
  return (uint32_t)(uintptr_t)p;
}
__device__ __forceinline__ f32x2 glb_load_b64(uint32_t voff, const void* base) {
  f32x2 d;
  asm volatile("global_load_dwordx2 %0, %1, %2" : "=v"(d) : "v"(voff), "s"(base));
  return d;
}
__device__ __forceinline__ void ds_write_b128_at(uint32_t addr, u32x4 v) {
  asm volatile("ds_write_b128 %0, %1" ::"v"(addr), "v"(v));
}
#define DSW32(A, D) asm volatile("ds_write_b32 %0, %1" ::"v"(A), "v"(D));
#define DSW64(A, D) asm volatile("ds_write_b64 %0, %1" ::"v"(A), "v"(D));
#define WAIT_VM(N)                                          \
  {                                                         \
    asm volatile("s_waitcnt vmcnt(" #N ")" ::: "memory");   \
    __builtin_amdgcn_sched_barrier(0);                      \
  }
#define WAIT_LGKM(N)                                        \
  {                                                         \
    asm volatile("s_waitcnt lgkmcnt(" #N ")" ::: "memory"); \
    __builtin_amdgcn_sched_barrier(0);                      \
  }
#define DSR64(D, A, OFF) \
  asm volatile("ds_read_b64 %0, %1 offset:" #OFF : "=v"(D) : "v"(A));
#define DSR128(D, A, OFF) \
  asm volatile("ds_read_b128 %0, %1 offset:" #OFF : "=v"(D) : "v"(A));
#define DS_READ_OFF(D, A, OFF) \
  asm volatile("ds_read_b32 %0, %1 offset:" #OFF : "=v"(D) : "v"(A));

// Packed fp32 add (two independent IEEE-rn adds; dataflow pins association).
__device__ __forceinline__ f32x2 pk_add(f32x2 a, f32x2 b) {
  f32x2 d;
  asm("v_pk_add_f32 %0, %1, %2" : "=v"(d) : "v"(a), "v"(b));
  return d;
}
__device__ __forceinline__ u64 rfl64(u64 x) {
  uint32_t lo = (uint32_t)__builtin_amdgcn_readfirstlane((int)(uint32_t)x);
  uint32_t hi = (uint32_t)__builtin_amdgcn_readfirstlane((int)(uint32_t)(x >> 32));
  return ((u64)hi << 32) | lo;
}
__device__ __forceinline__ uint32_t mbcnt64(u64 m) {
  uint32_t r = __builtin_amdgcn_mbcnt_lo((uint32_t)m, 0u);
  return __builtin_amdgcn_mbcnt_hi((uint32_t)(m >> 32), r);
}
// 64-lane DPP sum; result valid in lane 63 (same op sequence as rounds 1-7).
__device__ __forceinline__ float wave_red_add63(float v) {
#define DPP_ADD(c)                                                             \
  v += __int_as_float(                                                         \
      __builtin_amdgcn_update_dpp(0, __float_as_int(v), c, 0xF, 0xF, true))
  DPP_ADD(0x111);
  DPP_ADD(0x112);
  DPP_ADD(0x114);
  DPP_ADD(0x118);
  DPP_ADD(0x142);
  DPP_ADD(0x143);
#undef DPP_ADD
  return v;
}

// ---------------------------------------------------------------------------
// Kernel 0: transposed weights in workspace.
// w1t: 64 rows of 512B; rows 0..31 real, 32..63 zero (sentinels).
// w2t: 129 rows; rows 0..127 real, row 128 zero (sentinel).
// ---------------------------------------------------------------------------
__global__ __launch_bounds__(64) void snn_prep(const float* __restrict__ W1,
                                               const float* __restrict__ W2,
                                               f32x2* __restrict__ w1t,
                                               f32x2* __restrict__ w2t) {
  const int l = threadIdx.x;
  for (int j = 0; j < 64; ++j)
    w1t[j * 64 + l] = (j < 32) ? f32x2{W1[l * 32 + j], W1[(64 + l) * 32 + j]}
                               : f32x2{0.f, 0.f};
  for (int j = 0; j < 129; ++j)
    w2t[j * 64 + l] = (j < 128) ? f32x2{W2[l * 128 + j], W2[(64 + l) * 128 + j]}
                                : f32x2{0.f, 0.f};
}

// ---------------------------------------------------------------------------
// Kernel 1: delta encode -> 32-bit masks (verbatim from passing rounds 4-7).
// ---------------------------------------------------------------------------
__global__ __launch_bounds__(64) void snn_encode(const float* __restrict__ x,
                                                 uint32_t* __restrict__ masks) {
  __shared__ float tile[2][4][64][16];  // 32 KiB
  const int lane = threadIdx.x;
  const int sub = lane >> 4;
  const int f = lane & 15;
  const int b0 = blockIdx.x * 4;
  float ref = x[(size_t)(b0 + sub) * (TT * FDIM) + f];

  const float4* xv = (const float4*)x;
  float4 ld[16];
#define K1_ISSUE(G)                                                           \
  _Pragma("unroll") for (int k = 0; k < 16; ++k) {                            \
    int idx4 = k * 64 + lane;                                                 \
    int bl = idx4 >> 8;                                                       \
    int r = idx4 & 255;                                                       \
    ld[k] = xv[(size_t)(b0 + bl) * (TT * 4) + (size_t)(G) * 256 + r];         \
  }
#define K1_WRITE(BUF)                                                         \
  _Pragma("unroll") for (int k = 0; k < 16; ++k) {                            \
    int idx4 = k * 64 + lane;                                                 \
    int bl = idx4 >> 8;                                                       \
    int r = idx4 & 255;                                                       \
    ((float4*)&tile[BUF][bl][0][0])[r] = ld[k];                               \
  }
#define CHUNK_ISSUE(ARR, A)                                                   \
  {                                                                           \
    DS_READ_OFF(ARR[0], A, 0);                                                \
    DS_READ_OFF(ARR[1], A, 64);                                               \
    DS_READ_OFF(ARR[2], A, 128);                                              \
    DS_READ_OFF(ARR[3], A, 192);                                              \
    DS_READ_OFF(ARR[4], A, 256);                                              \
    DS_READ_OFF(ARR[5], A, 320);                                              \
    DS_READ_OFF(ARR[6], A, 384);                                              \
    DS_READ_OFF(ARR[7], A, 448);                                              \
  }
#define PROC8(ARR, TBASE)                                                     \
  _Pragma("unroll") for (int i = 0; i < 8; ++i) {                             \
    float cur = ARR[i];                                                       \
    float diff = cur - ref;                                                   \
    bool onb = diff >= 0.5f;                                                  \
    bool offb = diff <= -0.5f;                                                \
    u64 bon = __ballot(onb);                                                  \
    u64 boff = __ballot(offb);                                                \
    ref = (onb || offb) ? cur : ref;                                          \
    if (f == 0) {                                                             \
      uint32_t mk = (uint32_t)((bon >> (sub * 16)) & 0xFFFFull) |             \
                    ((uint32_t)((boff >> (sub * 16)) & 0xFFFFull) << 16);     \
      masks[(size_t)(b0 + sub) * TT + ((TBASE) + i)] = mk;                    \
    }                                                                         \
  }

  const uint32_t tbase =
      lds_addr32(&tile[0][0][0][0]) + (uint32_t)sub * 4096u + (uint32_t)f * 4u;

  K1_ISSUE(0);
  K1_WRITE(0);
  WAIT_LGKM(0);
  for (int g = 0; g < TT / 64; ++g) {
    if (g + 1 < TT / 64) K1_ISSUE(g + 1);
    const int buf = g & 1;
    const uint32_t caddr = tbase + (uint32_t)buf * 16384u;
    float va[8], vb[8];
    CHUNK_ISSUE(va, caddr);
#pragma unroll
    for (int c = 0; c < 8; ++c) {
      if (c < 7) {
        uint32_t an = caddr + (uint32_t)(c + 1) * 512u;
        if (c & 1) {
          CHUNK_ISSUE(va, an);
        } else {
          CHUNK_ISSUE(vb, an);
        }
        WAIT_LGKM(8);
      } else {
        WAIT_LGKM(0);
      }
      if (c & 1) {
        PROC8(vb, g * 64 + c * 8);
      } else {
        PROC8(va, g * 64 + c * 8);
      }
    }
    if (g + 1 < TT / 64) {
      K1_WRITE((g + 1) & 1);
      WAIT_LGKM(0);
    }
  }
#undef PROC8
#undef CHUNK_ISSUE
#undef K1_WRITE
#undef K1_ISSUE
}

// ---------------------------------------------------------------------------
// Kernel 2: specialized-wave SNN core with precomputed gather indices.
// One block (12 waves) per batch. iter k (one barrier at top, parity dbuf):
//   waves 0-9: C1(k) [16 idx-driven loads], C2(k-2) [24 idx-driven loads],
//              C3(k-4) DPP tasks
//   wave 10:   scan1(k-1): C1 -> LIF1 -> IDX1/S1R lists (mbcnt scatter)
//   wave 11:   IDX0(k+1) from input masks; scan2(k-3) -> S2; scan3(k-5) -> out
// Dependency audit (one barrier behind, parities disjoint):
//   IDX0(k)   written iter k-1 (wave 11)  -> read iter k (producers)
//   C1(k)     written iter k   (prod)     -> read iter k+1 (scan1)
//   IDX1(k-2) written iter k-1 (scan1)    -> read iter k (producers)
//   C2(k-2)   written iter k   (prod)     -> read iter k+1 (scan2 @ k-3+... )
//   S2(k-3)   written iter k   (scan2)    -> read iter k+1 (C3 @ k-4)
//   C3(k-4)   written iter k   (prod)     -> read iter k+1 (scan3 @ k-5)
// ---------------------------------------------------------------------------
__global__ __launch_bounds__(NTHR, 1) void snn_core8(
    const uint32_t* __restrict__ masks, const f32x2* __restrict__ w1t,
    const f32x2* __restrict__ w2t, const float* __restrict__ b1,
    const float* __restrict__ b2, const float* __restrict__ W3,
    const float* __restrict__ b3, float* __restrict__ out) {
  __shared__ __align__(16) uint32_t mks[TT];          // 16 KB input masks
  __shared__ f32x2 C1b[2][CH][64];                    // 32 KB
  __shared__ f32x2 C2b[2][CH][64];                    // 32 KB
  __shared__ f32x2 C3b[2][CH];                        // 512 B
  __shared__ __align__(16) u64 S2[2][CH][2];          // 1 KB spk2 ballots
  __shared__ __align__(16) uint32_t IDX0[2][CH][16];  // 4 KB w1t offsets
  __shared__ __align__(16) uint32_t IDX1[2][CH][24];  // 6 KB w2t offsets
  __shared__ __align__(16) u64 S1R[2][CH][2];         // 1 KB spk1 residuals

  const int tid = threadIdx.x;
  const int lane = tid & 63;
  const int wv = tid >> 6;
  const int b = blockIdx.x;
  const uint32_t lane8 = (uint32_t)lane * 8u;

  {  // stage this batch's masks into LDS (coalesced)
    const u32x4* src = (const u32x4*)(masks + (size_t)b * TT);
    u32x4* dst = (u32x4*)mks;
    for (int i = tid; i < TT / 4; i += NTHR) dst[i] = src[i];
  }
  const f32x2 bias1 = {b1[lane], b1[64 + lane]};
  const f32x2 bias2 = {b2[lane], b2[64 + lane]};
  const float w30a = W3[lane], w30b = W3[64 + lane];
  const float w31a = W3[128 + lane], w31b = W3[192 + lane];
  const float b30 = b3[0], b31 = b3[1];
  float m1a = 0.f, m1b = 0.f, m2a = 0.f, m2b = 0.f, m3x = 0.f, m3y = 0.f;
  float2* outv = (float2*)out;

  const uint32_t idx0b = lds_addr32(&IDX0[0][0][0]);
  const uint32_t idx1b = lds_addr32(&IDX1[0][0][0]);
  const uint32_t s1rb = lds_addr32(&S1R[0][0][0]);

// IDX0 builder (wave 11): expand input mask of chunk KK into 16 sentinel-
// padded w1t byte offsets per step via mbcnt rank scatter. O(1) per step.
#define IDX0_BUILD(KK)                                                        \
  if ((KK) >= 0 && (KK) < NCH) {                                              \
    const uint32_t p0_ = idx0b + (uint32_t)(((KK) & 1) * 2048);               \
    _Pragma("unroll") for (int i = 0; i < CH; ++i) {                          \
      uint32_t mk_ = mks[(KK)*CH + i];                                        \
      uint32_t ib_ = p0_ + (uint32_t)(i * 64);                                \
      if (lane < 16) { DSW32(ib_ + (uint32_t)lane * 4u, 16384u); }            \
      uint32_t r_ = __builtin_amdgcn_mbcnt_lo(mk_, 0u);                       \
      bool bt_ = (((u64)mk_ >> lane) & 1) != 0;                               \
      if (bt_) { DSW32(ib_ + r_ * 4u, (uint32_t)lane << 9); }                 \
    }                                                                         \
    WAIT_LGKM(0);                                                             \
  }

  __syncthreads();
  if (wv == 11) IDX0_BUILD(0);  // prime chunk 0 (published by loop-top barrier)

// ---- producer task helpers (vm ledger: 16 loads for C1, 24 for C2) ----
#define LD4_W1(Q, S0)                                                         \
  BUF[S0] = glb_load_b64(Q.x + lane8, w1t);                                   \
  BUF[S0 + 1] = glb_load_b64(Q.y + lane8, w1t);                               \
  BUF[S0 + 2] = glb_load_b64(Q.z + lane8, w1t);                               \
  BUF[S0 + 3] = glb_load_b64(Q.w + lane8, w1t);
#define LD4_W2(Q, S0)                                                         \
  BUF[S0] = glb_load_b64(Q.x + lane8, w2t);                                   \
  BUF[S0 + 1] = glb_load_b64(Q.y + lane8, w2t);                               \
  BUF[S0 + 2] = glb_load_b64(Q.z + lane8, w2t);                               \
  BUF[S0 + 3] = glb_load_b64(Q.w + lane8, w2t);
#define P_ISSUE(TASK, BUF, RA, RB)                                            \
  {                                                                           \
    if ((TASK) < CH) { /* C1 task, chunk k */                                 \
      if (k < NCH) {                                                          \
        uint32_t ib_ = idx0b + (uint32_t)((k & 1) * 2048) + (uint32_t)((TASK)*64); \
        u32x4 q0_, q1_, q2_, q3_;                                             \
        DSR128(q0_, ib_, 0);                                                  \
        DSR128(q1_, ib_, 16);                                                 \
        DSR128(q2_, ib_, 32);                                                 \
        DSR128(q3_, ib_, 48);                                                 \
        WAIT_LGKM(0);                                                         \
        LD4_W1(q0_, 0) LD4_W1(q1_, 4) LD4_W1(q2_, 8) LD4_W1(q3_, 12)          \
      } else {                                                                \
        _Pragma("unroll") for (int s = 0; s < 16; ++s) BUF[s] =               \
            glb_load_b64(16384u + lane8, w1t);                                \
      }                                                                       \
      RA = 0;                                                                 \
      RB = 0;                                                                 \
    } else { /* C2 task, chunk k-2 */                                         \
      int c2q_ = k - 2;                                                       \
      if (c2q_ >= 0 && c2q_ < NCH) {                                          \
        uint32_t ib_ = idx1b + (uint32_t)((c2q_ & 1) * 3072) +                \
                       (uint32_t)(((TASK)-CH) * 96);                          \
        uint32_t rq_ = s1rb + (uint32_t)((c2q_ & 1) * 512) +                  \
                       (uint32_t)(((TASK)-CH) * 16);                          \
        u32x4 q0_, q1_, q2_, q3_, q4_, q5_, qr_;                              \
        DSR128(q0_, ib_, 0);                                                  \
        DSR128(q1_, ib_, 16);                                                 \
        DSR128(q2_, ib_, 32);                                                 \
        DSR128(q3_, ib_, 48);                                                 \
        DSR128(q4_, ib_, 64);                                                 \
        DSR128(q5_, ib_, 80);                                                 \
        DSR128(qr_, rq_, 0);                                                  \
        WAIT_LGKM(0);                                                         \
        LD4_W2(q0_, 0) LD4_W2(q1_, 4) LD4_W2(q2_, 8)                          \
        LD4_W2(q3_, 12) LD4_W2(q4_, 16) LD4_W2(q5_, 20)                       \
        RA = (u64)qr_.x | ((u64)qr_.y << 32);                                 \
        RB = (u64)qr_.z | ((u64)qr_.w << 32);                                 \
      } else {                                                                \
        _Pragma("unroll") for (int s = 0; s < 24; ++s) BUF[s] =               \
            glb_load_b64(65536u + lane8, w2t);                                \
        RA = 0;                                                               \
        RB = 0;                                                               \
      }                                                                       \
    }                                                                         \
  }
#define P_CONSUME(TASK, BUF, RA, RB)                                          \
  {                                                                           \
    if ((TASK) < CH) {                                                        \
      if (k < NCH) {                                                          \
        f32x2 c_ = {0.f, 0.f};                                                \
        _Pragma("unroll") for (int s = 0; s < 16; ++s) c_ = pk_add(c_, BUF[s]); \
        c_ = pk_add(c_, bias1);                                               \
        C1b[k & 1][(TASK)][lane] = c_;                                        \
      }                                                                       \
    } else {                                                                  \
      int c2q_ = k - 2;                                                       \
      if (c2q_ >= 0 && c2q_ < NCH) {                                          \
        f32x2 c_ = {0.f, 0.f};                                                \
        _Pragma("unroll") for (int s = 0; s < 24; ++s) c_ = pk_add(c_, BUF[s]); \
        u64 ta_ = RA; /* rare >24-spike tails: exact ascending order */       \
        while (ta_) {                                                         \
          uint32_t j_ = (uint32_t)__builtin_ctzll(ta_);                       \
          ta_ &= ta_ - 1;                                                     \
          f32x2 tw_ = glb_load_b64((j_ << 9) + lane8, w2t);                   \
          WAIT_VM(0);                                                         \
          c_ = pk_add(c_, tw_);                                               \
        }                                                                     \
        u64 tb_ = RB;                                                         \
        while (tb_) {                                                         \
          uint32_t j_ = 64u + (uint32_t)__builtin_ctzll(tb_);                 \
          tb_ &= tb_ - 1;                                                     \
          f32x2 tw_ = glb_load_b64((j_ << 9) + lane8, w2t);                   \
          WAIT_VM(0);                                                         \
          c_ = pk_add(c_, tw_);                                               \
        }                                                                     \
        c_ = pk_add(c_, bias2);                                               \
        C2b[c2q_ & 1][(TASK)-CH][lane] = c_;                                  \
      }                                                                       \
    }                                                                         \
  }
#define C3_TASK(T3)                                                           \
  {                                                                           \
    int c3_ = k - 4;                                                          \
    if (c3_ >= 0 && c3_ < NCH) {                                              \
      u64 a_ = rfl64(S2[c3_ & 1][(T3)][0]);                                   \
      u64 b_ = rfl64(S2[c3_ & 1][(T3)][1]);                                   \
      float v0 = (((a_ >> lane) & 1) ? w30a : 0.f) +                          \
                 (((b_ >> lane) & 1) ? w30b : 0.f);                           \
      float v1 = (((a_ >> lane) & 1) ? w31a : 0.f) +                          \
                 (((b_ >> lane) & 1) ? w31b : 0.f);                           \
      float r0 = wave_red_add63(v0);                                          \
      float r1 = wave_red_add63(v1);                                          \
      if (lane == 63) C3b[c3_ & 1][(T3)] = f32x2{r0 + b30, r1 + b31};         \
    }                                                                         \
  }

// ---- scan helpers ----
#define ISSUE32_512(ARR, A)                                                   \
  {                                                                           \
    DSR64(ARR[0], A, 0);     DSR64(ARR[1], A, 512);                           \
    DSR64(ARR[2], A, 1024);  DSR64(ARR[3], A, 1536);                          \
    DSR64(ARR[4], A, 2048);  DSR64(ARR[5], A, 2560);                          \
    DSR64(ARR[6], A, 3072);  DSR64(ARR[7], A, 3584);                          \
    DSR64(ARR[8], A, 4096);  DSR64(ARR[9], A, 4608);                          \
    DSR64(ARR[10], A, 5120); DSR64(ARR[11], A, 5632);                         \
    DSR64(ARR[12], A, 6144); DSR64(ARR[13], A, 6656);                         \
    DSR64(ARR[14], A, 7168); DSR64(ARR[15], A, 7680);                         \
    DSR64(ARR[16], A, 8192); DSR64(ARR[17], A, 8704);                         \
    DSR64(ARR[18], A, 9216); DSR64(ARR[19], A, 9728);                         \
    DSR64(ARR[20], A, 10240); DSR64(ARR[21], A, 10752);                       \
    DSR64(ARR[22], A, 11264); DSR64(ARR[23], A, 11776);                       \
    DSR64(ARR[24], A, 12288); DSR64(ARR[25], A, 12800);                       \
    DSR64(ARR[26], A, 13312); DSR64(ARR[27], A, 13824);                       \
    DSR64(ARR[28], A, 14336); DSR64(ARR[29], A, 14848);                       \
    DSR64(ARR[30], A, 15360); DSR64(ARR[31], A, 15872);                       \
  }
#define ISSUE32_8(ARR, A)                                                     \
  {                                                                           \
    DSR64(ARR[0], A, 0);   DSR64(ARR[1], A, 8);                               \
    DSR64(ARR[2], A, 16);  DSR64(ARR[3], A, 24);                              \
    DSR64(ARR[4], A, 32);  DSR64(ARR[5], A, 40);                              \
    DSR64(ARR[6], A, 48);  DSR64(ARR[7], A, 56);                              \
    DSR64(ARR[8], A, 64);  DSR64(ARR[9], A, 72);                              \
    DSR64(ARR[10], A, 80); DSR64(ARR[11], A, 88);                             \
    DSR64(ARR[12], A, 96); DSR64(ARR[13], A, 104);                            \
    DSR64(ARR[14], A, 112); DSR64(ARR[15], A, 120);                           \
    DSR64(ARR[16], A, 128); DSR64(ARR[17], A, 136);                           \
    DSR64(ARR[18], A, 144); DSR64(ARR[19], A, 152);                           \
    DSR64(ARR[20], A, 160); DSR64(ARR[21], A, 168);                           \
    DSR64(ARR[22], A, 176); DSR64(ARR[23], A, 184);                           \
    DSR64(ARR[24], A, 192); DSR64(ARR[25], A, 200);                           \
    DSR64(ARR[26], A, 208); DSR64(ARR[27], A, 216);                           \
    DSR64(ARR[28], A, 224); DSR64(ARR[29], A, 232);                           \
    DSR64(ARR[30], A, 240); DSR64(ARR[31], A, 248);                           \
  }
// scan1: LIF1 over chunk CHK + mbcnt scatter of spike indices into IDX1,
// residual bits (rank>=24) into S1R. All per-step ds ops same-wave ordered.
#define SCAN1(CHK)                                                            \
  {                                                                           \
    const int par_ = (CHK) & 1;                                               \
    const uint32_t rb_ = lds_addr32(&C1b[par_][0][0]) + lane8;                \
    const uint32_t p1_ = idx1b + (uint32_t)(par_ * 3072);                     \
    const uint32_t pr_ = s1rb + (uint32_t)(par_ * 512);                       \
    f32x2 arr_[32];                                                           \
    ISSUE32_512(arr_, rb_);                                                   \
    WAIT_LGKM(0);                                                             \
    _Pragma("unroll") for (int i = 0; i < 32; ++i) {                          \
      f32x2 cv_ = arr_[i];                                                    \
      float n0_ = __fadd_rn(__fmul_rn(0.9f, m1a), cv_.x);                     \
      float n1_ = __fadd_rn(__fmul_rn(0.9f, m1b), cv_.y);                     \
      m1a = (m1a > 1.f) ? (n0_ - 1.f) : n0_;                                  \
      m1b = (m1b > 1.f) ? (n1_ - 1.f) : n1_;                                  \
      u64 s0_ = __ballot(m1a > 1.f);                                          \
      u64 s1_ = __ballot(m1b > 1.f);                                          \
      uint32_t ib_ = p1_ + (uint32_t)(i * 96);                                \
      if (lane < 24) { DSW32(ib_ + (uint32_t)lane * 4u, 65536u); }            \
      uint32_t r0_ = mbcnt64(s0_);                                            \
      bool b0_ = ((s0_ >> lane) & 1) != 0;                                    \
      if (b0_ && r0_ < 24u) { DSW32(ib_ + r0_ * 4u, (uint32_t)lane << 9); }   \
      uint32_t c0_ = (uint32_t)__builtin_popcountll(s0_);                     \
      uint32_t r1_ = c0_ + mbcnt64(s1_);                                      \
      bool b1_ = ((s1_ >> lane) & 1) != 0;                                    \
      if (b1_ && r1_ < 24u) {                                                 \
        DSW32(ib_ + r1_ * 4u, (uint32_t)(64 + lane) << 9);                    \
      }                                                                       \
      u64 e0_ = __ballot(b0_ && r0_ >= 24u);                                  \
      u64 e1_ = __ballot(b1_ && r1_ >= 24u);                                  \
      if (lane == 0) {                                                        \
        DSW64(pr_ + (uint32_t)(i * 16), e0_);                                 \
        DSW64(pr_ + (uint32_t)(i * 16 + 8), e1_);                             \
      }                                                                       \
    }                                                                         \
    WAIT_LGKM(0);                                                             \
  }
#define SCAN2(CHK)                                                            \
  {                                                                           \
    const int par_ = (CHK) & 1;                                               \
    const uint32_t rb_ = lds_addr32(&C2b[par_][0][0]) + lane8;                \
    const uint32_t sb_ = lds_addr32(&S2[par_][0][0]);                         \
    f32x2 arr_[32];                                                           \
    ISSUE32_512(arr_, rb_);                                                   \
    WAIT_LGKM(0);                                                             \
    _Pragma("unroll") for (int i = 0; i < 32; ++i) {                          \
      f32x2 cv_ = arr_[i];                                                    \
      float n0_ = __fadd_rn(__fmul_rn(0.9f, m2a), cv_.x);                     \
      float n1_ = __fadd_rn(__fmul_rn(0.9f, m2b), cv_.y);                     \
      m2a = (m2a > 1.f) ? (n0_ - 1.f) : n0_;                                  \
      m2b = (m2b > 1.f) ? (n1_ - 1.f) : n1_;                                  \
      u64 s0_ = __ballot(m2a > 1.f);                                          \
      u64 s1_ = __ballot(m2b > 1.f);                                          \
      if (lane == 0)                                                          \
        ds_write_b128_at(sb_ + (uint32_t)(i * 16),                            \
                         u32x4{(uint32_t)s0_, (uint32_t)(s0_ >> 32),          \
                               (uint32_t)s1_, (uint32_t)(s1_ >> 32)});        \
    }                                                                         \
    WAIT_LGKM(0);                                                             \
  }
#define SCAN3(CHK)                                                            \
  {                                                                           \
    const int par_ = (CHK) & 1;                                               \
    const uint32_t cb_ = lds_addr32(&C3b[par_][0]);                           \
    f32x2 arr_[32];                                                           \
    ISSUE32_8(arr_, cb_);                                                     \
    WAIT_LGKM(0);                                                             \
    _Pragma("unroll") for (int i = 0; i < 32; ++i) {                          \
      f32x2 c3_ = arr_[i];                                                    \
      float e0_ = __fadd_rn(__fmul_rn(0.9f, m3x), c3_.x);                     \
      float e1_ = __fadd_rn(__fmul_rn(0.9f, m3y), c3_.y);                     \
      m3x = (m3x > 1.f) ? (e0_ - 1.f) : e0_;                                  \
      m3y = (m3y > 1.f) ? (e1_ - 1.f) : e1_;                                  \
      if (lane == 0)                                                          \
        outv[(size_t)((CHK)*CH + i) * BB + b] = make_float2(m3x, m3y);        \
    }                                                                         \
  }

  // ================= chunk-synchronous main pipeline =================
  for (int k = 0; k < NCH + 5; ++k) {
    __syncthreads();
    if (wv < NPROD) {
      // tasks 0..31 = C1(chunk k) [16 loads], 32..63 = C2(chunk k-2) [24].
      // 2-deep ping-pong; wait count = loads of the just-issued task.
      f32x2 P[24], Q[24];
      u64 raP = 0, rbP = 0, raQ = 0, rbQ = 0;
      int ti = wv;
      {
        f32x2* BUF = P;
        P_ISSUE(ti, BUF, raP, rbP);
      }
      for (;;) {
        int tn = ti + NPROD;
        if (tn < 2 * CH) {
          f32x2* BUF = Q;
          P_ISSUE(tn, BUF, raQ, rbQ);
          if (tn < CH) {
            WAIT_VM(16);
          } else {
            WAIT_VM(24);
          }
        } else {
          WAIT_VM(0);
        }
        {
          f32x2* BUF = P;
          P_CONSUME(ti, BUF, raP, rbP);
        }
        if (tn >= 2 * CH) break;
        ti = tn + NPROD;
        if (ti < 2 * CH) {
          f32x2* BUF = P;
          P_ISSUE(ti, BUF, raP, rbP);
          if (ti < CH) {
            WAIT_VM(16);
          } else {
            WAIT_VM(24);
          }
        } else {
          WAIT_VM(0);
        }
        {
          f32x2* BUF = Q;
          P_CONSUME(tn, BUF, raQ, rbQ);
        }
        if (ti >= 2 * CH) break;
      }
      for (int t3 = wv; t3 < CH; t3 += NPROD) {
        C3_TASK(t3);
      }
    } else if (wv == 10) {
      if (k >= 1 && k - 1 < NCH) SCAN1(k - 1);
    } else {
      IDX0_BUILD(k + 1);
      if (k >= 3 && k - 3 < NCH) SCAN2(k - 3);
      if (k >= 5 && k - 5 < NCH) SCAN3(k - 5);
    }
  }
#undef SCAN3
#undef SCAN2
#undef SCAN1
#undef ISSUE32_8
#undef ISSUE32_512
#undef C3_TASK
#undef P_CONSUME
#undef P_ISSUE
#undef LD4_W2
#undef LD4_W1
#undef IDX0_BUILD
}

extern "C" void kernel_launch(void* const* d_in, const int* in_sizes, int n_in,
                              void* d_out, int out_size, void* d_ws,
                              size_t ws_size, hipStream_t stream) {
  const float* x = (const float*)d_in[0];
  const float* W1 = (const float*)d_in[1];
  const float* b1 = (const float*)d_in[2];
  const float* W2 = (const float*)d_in[3];
  const float* b2 = (const float*)d_in[4];
  const float* W3 = (const float*)d_in[5];
  const float* b3 = (const float*)d_in[6];
  float* out = (float*)d_out;

  uint32_t* masks = (uint32_t*)d_ws;                         // 4 MiB
  char* wbase = (char*)d_ws + (size_t)BB * TT * 4;
  f32x2* w1t = (f32x2*)wbase;                                // 32768 B
  f32x2* w2t = (f32x2*)(wbase + 32768);                      // 66048 B

  snn_prep<<<1, 64, 0, stream>>>(W1, W2, w1t, w2t);
  snn_encode<<<BB / 4, 64, 0, stream>>>(x, masks);
  snn_core8<<<BB, NTHR, 0, stream>>>(masks, w1t, w2t, b1, b2, W3, b3, out);
}

// Round 10
// 1595.853 us; speedup vs baseline: 1.5788x; 1.0341x over previous
//
#include <hip/hip_runtime.h>
#include <cstdint>

#define BB 256
#define TT 4096
#define FDIM 16
#define HH 128
#define CH 32           // timesteps per chunk
#define NCH (TT / CH)   // 128 chunks
#define NPROD 14        // producer waves 0-13; wave 14 = scan1, wave 15 = aux
#define NTHR 1024

typedef unsigned long long u64;
typedef float f32x2 __attribute__((ext_vector_type(2)));
typedef uint32_t u32x4 __attribute__((ext_vector_type(4)));

// ---------------------------------------------------------------------------
// asm helpers. Loads are asm volatile with explicit waits; SAFETY RULE from
// round-9 failure: every asm-load's consuming region must keep total live
// VGPRs well under the occupancy cap, so the compiler never copies/spills an
// asm-output register before the wait executes. All task bodies here peak
// at ~60-90 VGPR vs the 128 cap.
// ---------------------------------------------------------------------------
__device__ __forceinline__ uint32_t lds_addr32(const void* p) {
  return (uint32_t)(uintptr_t)p;
}
__device__ __forceinline__ f32x2 glb_load_b64(uint32_t voff, const void* base) {
  f32x2 d;
  asm volatile("global_load_dwordx2 %0, %1, %2" : "=v"(d) : "v"(voff), "s"(base));
  return d;
}
__device__ __forceinline__ void ds_write_b128_at(uint32_t addr, u32x4 v) {
  asm volatile("ds_write_b128 %0, %1" ::"v"(addr), "v"(v));
}
#define DSW32(A, D) asm volatile("ds_write_b32 %0, %1" ::"v"(A), "v"(D));
#define DSW64(A, D) asm volatile("ds_write_b64 %0, %1" ::"v"(A), "v"(D));
#define WAIT_VM(N)                                          \
  {                                                         \
    asm volatile("s_waitcnt vmcnt(" #N ")" ::: "memory");   \
    __builtin_amdgcn_sched_barrier(0);                      \
  }
#define WAIT_LGKM(N)                                        \
  {                                                         \
    asm volatile("s_waitcnt lgkmcnt(" #N ")" ::: "memory"); \
    __builtin_amdgcn_sched_barrier(0);                      \
  }
#define DSR64(D, A, OFF) \
  asm volatile("ds_read_b64 %0, %1 offset:" #OFF : "=v"(D) : "v"(A));
#define DSR128(D, A, OFF) \
  asm volatile("ds_read_b128 %0, %1 offset:" #OFF : "=v"(D) : "v"(A));
#define DS_READ_OFF(D, A, OFF) \
  asm volatile("ds_read_b32 %0, %1 offset:" #OFF : "=v"(D) : "v"(A));

// Packed fp32 add (two independent IEEE-rn adds; dataflow pins association).
__device__ __forceinline__ f32x2 pk_add(f32x2 a, f32x2 b) {
  f32x2 d;
  asm("v_pk_add_f32 %0, %1, %2" : "=v"(d) : "v"(a), "v"(b));
  return d;
}
__device__ __forceinline__ u64 rfl64(u64 x) {
  uint32_t lo = (uint32_t)__builtin_amdgcn_readfirstlane((int)(uint32_t)x);
  uint32_t hi = (uint32_t)__builtin_amdgcn_readfirstlane((int)(uint32_t)(x >> 32));
  return ((u64)hi << 32) | lo;
}
__device__ __forceinline__ uint32_t mbcnt64(u64 m) {
  uint32_t r = __builtin_amdgcn_mbcnt_lo((uint32_t)m, 0u);
  return __builtin_amdgcn_mbcnt_hi((uint32_t)(m >> 32), r);
}
// 64-lane DPP sum; result valid in lane 63 (same op sequence as rounds 1-8).
__device__ __forceinline__ float wave_red_add63(float v) {
#define DPP_ADD(c)                                                             \
  v += __int_as_float(                                                         \
      __builtin_amdgcn_update_dpp(0, __float_as_int(v), c, 0xF, 0xF, true))
  DPP_ADD(0x111);
  DPP_ADD(0x112);
  DPP_ADD(0x114);
  DPP_ADD(0x118);
  DPP_ADD(0x142);
  DPP_ADD(0x143);
#undef DPP_ADD
  return v;
}

// ---------------------------------------------------------------------------
// Kernel 0: transposed weights in workspace.
// w1t: 64 rows of 512B; rows 0..31 real, 32..63 zero (sentinels).
// w2t: 129 rows; rows 0..127 real, row 128 zero (sentinel).
// ---------------------------------------------------------------------------
__global__ __launch_bounds__(64) void snn_prep(const float* __restrict__ W1,
                                               const float* __restrict__ W2,
                                               f32x2* __restrict__ w1t,
                                               f32x2* __restrict__ w2t) {
  const int l = threadIdx.x;
  for (int j = 0; j < 64; ++j)
    w1t[j * 64 + l] = (j < 32) ? f32x2{W1[l * 32 + j], W1[(64 + l) * 32 + j]}
                               : f32x2{0.f, 0.f};
  for (int j = 0; j < 129; ++j)
    w2t[j * 64 + l] = (j < 128) ? f32x2{W2[l * 128 + j], W2[(64 + l) * 128 + j]}
                                : f32x2{0.f, 0.f};
}

// ---------------------------------------------------------------------------
// Kernel 1: delta encode -> 32-bit masks (verbatim from passing rounds 4-8;
// low register pressure -> no spill hazard).
// ---------------------------------------------------------------------------
__global__ __launch_bounds__(64) void snn_encode(const float* __restrict__ x,
                                                 uint32_t* __restrict__ masks) {
  __shared__ float tile[2][4][64][16];  // 32 KiB
  const int lane = threadIdx.x;
  const int sub = lane >> 4;
  const int f = lane & 15;
  const int b0 = blockIdx.x * 4;
  float ref = x[(size_t)(b0 + sub) * (TT * FDIM) + f];

  const float4* xv = (const float4*)x;
  float4 ld[16];
#define K1_ISSUE(G)                                                           \
  _Pragma("unroll") for (int k = 0; k < 16; ++k) {                            \
    int idx4 = k * 64 + lane;                                                 \
    int bl = idx4 >> 8;                                                       \
    int r = idx4 & 255;                                                       \
    ld[k] = xv[(size_t)(b0 + bl) * (TT * 4) + (size_t)(G) * 256 + r];         \
  }
#define K1_WRITE(BUF)                                                         \
  _Pragma("unroll") for (int k = 0; k < 16; ++k) {                            \
    int idx4 = k * 64 + lane;                                                 \
    int bl = idx4 >> 8;                                                       \
    int r = idx4 & 255;                                                       \
    ((float4*)&tile[BUF][bl][0][0])[r] = ld[k];                               \
  }
#define CHUNK_ISSUE(ARR, A)                                                   \
  {                                                                           \
    DS_READ_OFF(ARR[0], A, 0);                                                \
    DS_READ_OFF(ARR[1], A, 64);                                               \
    DS_READ_OFF(ARR[2], A, 128);                                              \
    DS_READ_OFF(ARR[3], A, 192);                                              \
    DS_READ_OFF(ARR[4], A, 256);                                              \
    DS_READ_OFF(ARR[5], A, 320);                                              \
    DS_READ_OFF(ARR[6], A, 384);                                              \
    DS_READ_OFF(ARR[7], A, 448);                                              \
  }
#define PROC8(ARR, TBASE)                                                     \
  _Pragma("unroll") for (int i = 0; i < 8; ++i) {                             \
    float cur = ARR[i];                                                       \
    float diff = cur - ref;                                                   \
    bool onb = diff >= 0.5f;                                                  \
    bool offb = diff <= -0.5f;                                                \
    u64 bon = __ballot(onb);                                                  \
    u64 boff = __ballot(offb);                                                \
    ref = (onb || offb) ? cur : ref;                                          \
    if (f == 0) {                                                             \
      uint32_t mk = (uint32_t)((bon >> (sub * 16)) & 0xFFFFull) |             \
                    ((uint32_t)((boff >> (sub * 16)) & 0xFFFFull) << 16);     \
      masks[(size_t)(b0 + sub) * TT + ((TBASE) + i)] = mk;                    \
    }                                                                         \
  }

  const uint32_t tbase =
      lds_addr32(&tile[0][0][0][0]) + (uint32_t)sub * 4096u + (uint32_t)f * 4u;

  K1_ISSUE(0);
  K1_WRITE(0);
  WAIT_LGKM(0);
  for (int g = 0; g < TT / 64; ++g) {
    if (g + 1 < TT / 64) K1_ISSUE(g + 1);
    const int buf = g & 1;
    const uint32_t caddr = tbase + (uint32_t)buf * 16384u;
    float va[8], vb[8];
    CHUNK_ISSUE(va, caddr);
#pragma unroll
    for (int c = 0; c < 8; ++c) {
      if (c < 7) {
        uint32_t an = caddr + (uint32_t)(c + 1) * 512u;
        if (c & 1) {
          CHUNK_ISSUE(va, an);
        } else {
          CHUNK_ISSUE(vb, an);
        }
        WAIT_LGKM(8);
      } else {
        WAIT_LGKM(0);
      }
      if (c & 1) {
        PROC8(vb, g * 64 + c * 8);
      } else {
        PROC8(va, g * 64 + c * 8);
      }
    }
    if (g + 1 < TT / 64) {
      K1_WRITE((g + 1) & 1);
      WAIT_LGKM(0);
    }
  }
#undef PROC8
#undef CHUNK_ISSUE
#undef K1_WRITE
#undef K1_ISSUE
}

// ---------------------------------------------------------------------------
// Kernel 2: specialized-wave SNN core, 16 waves/block, one block per batch.
// Same parity/dependency scheme as passing round 8. Producer tasks are now
// self-contained (issue -> WAIT_VM(0) -> sum): no cross-task ledger, low
// register pressure, no spill hazard. Out-of-range tasks skip entirely.
// ---------------------------------------------------------------------------
__global__ __launch_bounds__(NTHR, 1) void snn_core10(
    const uint32_t* __restrict__ masks, const f32x2* __restrict__ w1t,
    const f32x2* __restrict__ w2t, const float* __restrict__ b1,
    const float* __restrict__ b2, const float* __restrict__ W3,
    const float* __restrict__ b3, float* __restrict__ out) {
  __shared__ __align__(16) uint32_t mks[TT];          // 16 KB input masks
  __shared__ f32x2 C1b[2][CH][64];                    // 32 KB
  __shared__ f32x2 C2b[2][CH][64];                    // 32 KB
  __shared__ f32x2 C3b[2][CH];                        // 512 B
  __shared__ __align__(16) u64 S2[2][CH][2];          // 1 KB spk2 ballots
  __shared__ __align__(16) uint32_t IDX0[2][CH][16];  // 4 KB w1t offsets
  __shared__ __align__(16) uint32_t IDX1[2][CH][24];  // 6 KB w2t offsets
  __shared__ __align__(16) u64 S1R[2][CH][2];         // 1 KB spk1 residuals

  const int tid = threadIdx.x;
  const int lane = tid & 63;
  const int wv = tid >> 6;
  const int b = blockIdx.x;
  const uint32_t lane8 = (uint32_t)lane * 8u;

  {  // stage this batch's masks into LDS (coalesced)
    const u32x4* src = (const u32x4*)(masks + (size_t)b * TT);
    u32x4* dst = (u32x4*)mks;
    for (int i = tid; i < TT / 4; i += NTHR) dst[i] = src[i];
  }
  const f32x2 bias1 = {b1[lane], b1[64 + lane]};
  const f32x2 bias2 = {b2[lane], b2[64 + lane]};
  const float w30a = W3[lane], w30b = W3[64 + lane];
  const float w31a = W3[128 + lane], w31b = W3[192 + lane];
  const float b30 = b3[0], b31 = b3[1];
  float m1a = 0.f, m1b = 0.f, m2a = 0.f, m2b = 0.f, m3x = 0.f, m3y = 0.f;
  float2* outv = (float2*)out;

  const uint32_t idx0b = lds_addr32(&IDX0[0][0][0]);
  const uint32_t idx1b = lds_addr32(&IDX1[0][0][0]);
  const uint32_t s1rb = lds_addr32(&S1R[0][0][0]);

// IDX0 builder (wave 15): expand input mask of chunk KK into 16 sentinel-
// padded w1t byte offsets per step via mbcnt rank scatter. O(1) per step.
#define IDX0_BUILD(KK)                                                        \
  if ((KK) >= 0 && (KK) < NCH) {                                              \
    const uint32_t p0_ = idx0b + (uint32_t)(((KK) & 1) * 2048);               \
    _Pragma("unroll") for (int i = 0; i < CH; ++i) {                          \
      uint32_t mk_ = mks[(KK)*CH + i];                                        \
      uint32_t ib_ = p0_ + (uint32_t)(i * 64);                                \
      if (lane < 16) { DSW32(ib_ + (uint32_t)lane * 4u, 16384u); }            \
      uint32_t r_ = __builtin_amdgcn_mbcnt_lo(mk_, 0u);                       \
      bool bt_ = (((u64)mk_ >> lane) & 1) != 0;                               \
      if (bt_) { DSW32(ib_ + r_ * 4u, (uint32_t)lane << 9); }                 \
    }                                                                         \
    WAIT_LGKM(0);                                                             \
  }

  __syncthreads();
  if (wv == 15) IDX0_BUILD(0);  // prime chunk 0 (published by loop-top barrier)

// ---- producer tasks: self-contained, WAIT_VM(0) before consume ----
#define LD4_W1(Q, S0)                                                         \
  B[S0] = glb_load_b64(Q.x + lane8, w1t);                                     \
  B[S0 + 1] = glb_load_b64(Q.y + lane8, w1t);                                 \
  B[S0 + 2] = glb_load_b64(Q.z + lane8, w1t);                                 \
  B[S0 + 3] = glb_load_b64(Q.w + lane8, w1t);
#define LD4_W2(Q, S0)                                                         \
  B[S0] = glb_load_b64(Q.x + lane8, w2t);                                     \
  B[S0 + 1] = glb_load_b64(Q.y + lane8, w2t);                                 \
  B[S0 + 2] = glb_load_b64(Q.z + lane8, w2t);                                 \
  B[S0 + 3] = glb_load_b64(Q.w + lane8, w2t);
#define C1_TASK(TASK)                                                         \
  {                                                                           \
    uint32_t ib_ = idx0b + (uint32_t)((k & 1) * 2048) + (uint32_t)((TASK)*64);\
    u32x4 q0_, q1_, q2_, q3_;                                                 \
    DSR128(q0_, ib_, 0);                                                      \
    DSR128(q1_, ib_, 16);                                                     \
    DSR128(q2_, ib_, 32);                                                     \
    DSR128(q3_, ib_, 48);                                                     \
    WAIT_LGKM(0);                                                             \
    f32x2 B[16];                                                              \
    LD4_W1(q0_, 0) LD4_W1(q1_, 4) LD4_W1(q2_, 8) LD4_W1(q3_, 12)              \
    WAIT_VM(0);                                                               \
    f32x2 c_ = {0.f, 0.f};                                                    \
    _Pragma("unroll") for (int s = 0; s < 16; ++s) c_ = pk_add(c_, B[s]);     \
    c_ = pk_add(c_, bias1);                                                   \
    C1b[k & 1][(TASK)][lane] = c_;                                            \
  }
#define C2_TASK(TASK, C2Q)                                                    \
  {                                                                           \
    uint32_t ib_ = idx1b + (uint32_t)(((C2Q)&1) * 3072) + (uint32_t)((TASK)*96); \
    uint32_t rq_ = s1rb + (uint32_t)(((C2Q)&1) * 512) + (uint32_t)((TASK)*16);\
    u32x4 q0_, q1_, q2_, q3_, q4_, q5_, qr_;                                  \
    DSR128(q0_, ib_, 0);                                                      \
    DSR128(q1_, ib_, 16);                                                     \
    DSR128(q2_, ib_, 32);                                                     \
    DSR128(q3_, ib_, 48);                                                     \
    DSR128(q4_, ib_, 64);                                                     \
    DSR128(q5_, ib_, 80);                                                     \
    DSR128(qr_, rq_, 0);                                                      \
    WAIT_LGKM(0);                                                             \
    f32x2 B[24];                                                              \
    LD4_W2(q0_, 0) LD4_W2(q1_, 4) LD4_W2(q2_, 8)                              \
    LD4_W2(q3_, 12) LD4_W2(q4_, 16) LD4_W2(q5_, 20)                           \
    u64 ta_ = (u64)qr_.x | ((u64)qr_.y << 32);                                \
    u64 tb_ = (u64)qr_.z | ((u64)qr_.w << 32);                                \
    WAIT_VM(0);                                                               \
    f32x2 c_ = {0.f, 0.f};                                                    \
    _Pragma("unroll") for (int s = 0; s < 24; ++s) c_ = pk_add(c_, B[s]);     \
    while (ta_) { /* rare >24-spike tails: exact ascending order */           \
      uint32_t j_ = (uint32_t)__builtin_ctzll(ta_);                           \
      ta_ &= ta_ - 1;                                                         \
      f32x2 tw_ = glb_load_b64((j_ << 9) + lane8, w2t);                       \
      WAIT_VM(0);                                                             \
      c_ = pk_add(c_, tw_);                                                   \
    }                                                                         \
    while (tb_) {                                                             \
      uint32_t j_ = 64u + (uint32_t)__builtin_ctzll(tb_);                     \
      tb_ &= tb_ - 1;                                                         \
      f32x2 tw_ = glb_load_b64((j_ << 9) + lane8, w2t);                       \
      WAIT_VM(0);                                                             \
      c_ = pk_add(c_, tw_);                                                   \
    }                                                                         \
    c_ = pk_add(c_, bias2);                                                   \
    C2b[(C2Q)&1][(TASK)][lane] = c_;                                          \
  }
#define C3_TASK(T3)                                                           \
  {                                                                           \
    int c3_ = k - 4;                                                          \
    if (c3_ >= 0 && c3_ < NCH) {                                              \
      u64 a_ = rfl64(S2[c3_ & 1][(T3)][0]);                                   \
      u64 b_ = rfl64(S2[c3_ & 1][(T3)][1]);                                   \
      float v0 = (((a_ >> lane) & 1) ? w30a : 0.f) +                          \
                 (((b_ >> lane) & 1) ? w30b : 0.f);                           \
      float v1 = (((a_ >> lane) & 1) ? w31a : 0.f) +                          \
                 (((b_ >> lane) & 1) ? w31b : 0.f);                           \
      float r0 = wave_red_add63(v0);                                          \
      float r1 = wave_red_add63(v1);                                          \
      if (lane == 63) C3b[c3_ & 1][(T3)] = f32x2{r0 + b30, r1 + b31};         \
    }                                                                         \
  }

// ---- scan helpers: 16-wide issue groups (low register pressure) ----
#define ISSUE16_512(ARR, A)                                                   \
  {                                                                           \
    DSR64(ARR[0], A, 0);     DSR64(ARR[1], A, 512);                           \
    DSR64(ARR[2], A, 1024);  DSR64(ARR[3], A, 1536);                          \
    DSR64(ARR[4], A, 2048);  DSR64(ARR[5], A, 2560);                          \
    DSR64(ARR[6], A, 3072);  DSR64(ARR[7], A, 3584);                          \
    DSR64(ARR[8], A, 4096);  DSR64(ARR[9], A, 4608);                          \
    DSR64(ARR[10], A, 5120); DSR64(ARR[11], A, 5632);                         \
    DSR64(ARR[12], A, 6144); DSR64(ARR[13], A, 6656);                         \
    DSR64(ARR[14], A, 7168); DSR64(ARR[15], A, 7680);                         \
  }
#define ISSUE16_8(ARR, A)                                                     \
  {                                                                           \
    DSR64(ARR[0], A, 0);   DSR64(ARR[1], A, 8);                               \
    DSR64(ARR[2], A, 16);  DSR64(ARR[3], A, 24);                              \
    DSR64(ARR[4], A, 32);  DSR64(ARR[5], A, 40);                              \
    DSR64(ARR[6], A, 48);  DSR64(ARR[7], A, 56);                              \
    DSR64(ARR[8], A, 64);  DSR64(ARR[9], A, 72);                              \
    DSR64(ARR[10], A, 80); DSR64(ARR[11], A, 88);                             \
    DSR64(ARR[12], A, 96); DSR64(ARR[13], A, 104);                            \
    DSR64(ARR[14], A, 112); DSR64(ARR[15], A, 120);                           \
  }
// scan1 half: 16 LIF1 steps + mbcnt scatter into IDX1/S1R.
#define SCAN1_HALF(P1, PR, TB)                                                \
  _Pragma("unroll") for (int i = 0; i < 16; ++i) {                            \
    f32x2 cv_ = arr_[i];                                                      \
    float n0_ = __fadd_rn(__fmul_rn(0.9f, m1a), cv_.x);                       \
    float n1_ = __fadd_rn(__fmul_rn(0.9f, m1b), cv_.y);                       \
    m1a = (m1a > 1.f) ? (n0_ - 1.f) : n0_;                                    \
    m1b = (m1b > 1.f) ? (n1_ - 1.f) : n1_;                                    \
    u64 s0_ = __ballot(m1a > 1.f);                                            \
    u64 s1_ = __ballot(m1b > 1.f);                                            \
    uint32_t ib_ = (P1) + (uint32_t)(((TB) + i) * 96);                        \
    if (lane < 24) { DSW32(ib_ + (uint32_t)lane * 4u, 65536u); }              \
    uint32_t r0_ = mbcnt64(s0_);                                              \
    bool b0_ = ((s0_ >> lane) & 1) != 0;                                      \
    if (b0_ && r0_ < 24u) { DSW32(ib_ + r0_ * 4u, (uint32_t)lane << 9); }     \
    uint32_t c0_ = (uint32_t)__builtin_popcountll(s0_);                       \
    uint32_t r1_ = c0_ + mbcnt64(s1_);                                        \
    bool b1_ = ((s1_ >> lane) & 1) != 0;                                      \
    if (b1_ && r1_ < 24u) {                                                   \
      DSW32(ib_ + r1_ * 4u, (uint32_t)(64 + lane) << 9);                      \
    }                                                                         \
    u64 e0_ = __ballot(b0_ && r0_ >= 24u);                                    \
    u64 e1_ = __ballot(b1_ && r1_ >= 24u);                                    \
    if (lane == 0) {                                                          \
      DSW64((PR) + (uint32_t)(((TB) + i) * 16), e0_);                         \
      DSW64((PR) + (uint32_t)(((TB) + i) * 16 + 8), e1_);                     \
    }                                                                         \
  }
#define SCAN1(CHK)                                                            \
  {                                                                           \
    const int par_ = (CHK) & 1;                                               \
    const uint32_t rb_ = lds_addr32(&C1b[par_][0][0]) + lane8;                \
    const uint32_t p1_ = idx1b + (uint32_t)(par_ * 3072);                     \
    const uint32_t pr_ = s1rb + (uint32_t)(par_ * 512);                       \
    f32x2 arr_[16];                                                           \
    ISSUE16_512(arr_, rb_);                                                   \
    WAIT_LGKM(0);                                                             \
    SCAN1_HALF(p1_, pr_, 0)                                                   \
    const uint32_t rb2_ = rb_ + 8192u;                                        \
    ISSUE16_512(arr_, rb2_);                                                  \
    WAIT_LGKM(0);                                                             \
    SCAN1_HALF(p1_, pr_, 16)                                                  \
    WAIT_LGKM(0);                                                             \
  }
#define SCAN2_HALF(SB, TB)                                                    \
  _Pragma("unroll") for (int i = 0; i < 16; ++i) {                            \
    f32x2 cv_ = arr_[i];                                                      \
    float n0_ = __fadd_rn(__fmul_rn(0.9f, m2a), cv_.x);                       \
    float n1_ = __fadd_rn(__fmul_rn(0.9f, m2b), cv_.y);                       \
    m2a = (m2a > 1.f) ? (n0_ - 1.f) : n0_;                                    \
    m2b = (m2b > 1.f) ? (n1_ - 1.f) : n1_;                                    \
    u64 s0_ = __ballot(m2a > 1.f);                                            \
    u64 s1_ = __ballot(m2b > 1.f);                                            \
    if (lane == 0)                                                            \
      ds_write_b128_at((SB) + (uint32_t)(((TB) + i) * 16),                    \
                       u32x4{(uint32_t)s0_, (uint32_t)(s0_ >> 32),            \
                             (uint32_t)s1_, (uint32_t)(s1_ >> 32)});          \
  }
#define SCAN2(CHK)                                                            \
  {                                                                           \
    const int par_ = (CHK) & 1;                                               \
    const uint32_t rb_ = lds_addr32(&C2b[par_][0][0]) + lane8;                \
    const uint32_t sb_ = lds_addr32(&S2[par_][0][0]);                         \
    f32x2 arr_[16];                                                           \
    ISSUE16_512(arr_, rb_);                                                   \
    WAIT_LGKM(0);                                                             \
    SCAN2_HALF(sb_, 0)                                                        \
    const uint32_t rb2_ = rb_ + 8192u;                                        \
    ISSUE16_512(arr_, rb2_);                                                  \
    WAIT_LGKM(0);                                                             \
    SCAN2_HALF(sb_, 16)                                                       \
    WAIT_LGKM(0);                                                             \
  }
#define SCAN3_HALF(CHK, TB)                                                   \
  _Pragma("unroll") for (int i = 0; i < 16; ++i) {                            \
    f32x2 c3_ = arr_[i];                                                      \
    float e0_ = __fadd_rn(__fmul_rn(0.9f, m3x), c3_.x);                       \
    float e1_ = __fadd_rn(__fmul_rn(0.9f, m3y), c3_.y);                       \
    m3x = (m3x > 1.f) ? (e0_ - 1.f) : e0_;                                    \
    m3y = (m3y > 1.f) ? (e1_ - 1.f) : e1_;                                    \
    if (lane == 0)                                                            \
      outv[(size_t)((CHK)*CH + (TB) + i) * BB + b] = make_float2(m3x, m3y);   \
  }
#define SCAN3(CHK)                                                            \
  {                                                                           \
    const int par_ = (CHK) & 1;                                               \
    const uint32_t cb_ = lds_addr32(&C3b[par_][0]);                           \
    f32x2 arr_[16];                                                           \
    ISSUE16_8(arr_, cb_);                                                     \
    WAIT_LGKM(0);                                                             \
    SCAN3_HALF(CHK, 0)                                                        \
    const uint32_t cb2_ = cb_ + 128u;                                         \
    ISSUE16_8(arr_, cb2_);                                                    \
    WAIT_LGKM(0);                                                             \
    SCAN3_HALF(CHK, 16)                                                       \
  }

  // ================= chunk-synchronous main pipeline =================
  for (int k = 0; k < NCH + 5; ++k) {
    __syncthreads();
    if (wv < NPROD) {
      // tasks 0..31 = C1(chunk k), 32..63 = C2(chunk k-2); skip out-of-range.
      for (int ti = wv; ti < 2 * CH; ti += NPROD) {
        if (ti < CH) {
          if (k < NCH) C1_TASK(ti);
        } else {
          int c2q = k - 2;
          if (c2q >= 0 && c2q < NCH) C2_TASK(ti - CH, c2q);
        }
      }
      for (int t3 = wv; t3 < CH; t3 += NPROD) {
        C3_TASK(t3);
      }
    } else if (wv == 14) {
      if (k >= 1 && k - 1 < NCH) SCAN1(k - 1);
    } else {
      IDX0_BUILD(k + 1);
      if (k >= 3 && k - 3 < NCH) SCAN2(k - 3);
      if (k >= 5 && k - 5 < NCH) SCAN3(k - 5);
    }
  }
#undef SCAN3
#undef SCAN3_HALF
#undef SCAN2
#undef SCAN2_HALF
#undef SCAN1
#undef SCAN1_HALF
#undef ISSUE16_8
#undef ISSUE16_512
#undef C3_TASK
#undef C2_TASK
#undef C1_TASK
#undef LD4_W2
#undef LD4_W1
#undef IDX0_BUILD
}

extern "C" void kernel_launch(void* const* d_in, const int* in_sizes, int n_in,
                              void* d_out, int out_size, void* d_ws,
                              size_t ws_size, hipStream_t stream) {
  const float* x = (const float*)d_in[0];
  const float* W1 = (const float*)d_in[1];
  const float* b1 = (const float*)d_in[2];
  const float* W2 = (const float*)d_in[3];
  const float* b2 = (const float*)d_in[4];
  const float* W3 = (const float*)d_in[5];
  const float* b3 = (const float*)d_in[6];
  float* out = (float*)d_out;

  uint32_t* masks = (uint32_t*)d_ws;                         // 4 MiB
  char* wbase = (char*)d_ws + (size_t)BB * TT * 4;
  f32x2* w1t = (f32x2*)wbase;                                // 32768 B
  f32x2* w2t = (f32x2*)(wbase + 32768);                      // 66048 B

  snn_prep<<<1, 64, 0, stream>>>(W1, W2, w1t, w2t);
  snn_encode<<<BB / 4, 64, 0, stream>>>(x, masks);
  snn_core10<<<BB, NTHR, 0, stream>>>(masks, w1t, w2t, b1, b2, W3, b3, out);
}